// Round 6
// baseline (348.408 us; speedup 1.0000x reference)
//
#include <hip/hip_runtime.h>
#include <math.h>

// Direct-gather pooler: no LDS, no global_load_lds, no explicit waitcnt.
// Per lane (= one of 49 output bins): 16 channel-invariant tap offsets + weights,
// per channel: 16 direct global loads + 16 FMA + masked store.
// Channels processed in pairs -> 32 independent loads in flight per wave.

// 49-lane output: out[n][c][ph][pw], lane = ph*7+pw

__global__ __launch_bounds__(128) void pooler_kernel(
    const float* __restrict__ f0, const float* __restrict__ f1,
    const float* __restrict__ f2, const float* __restrict__ f3,
    const float* __restrict__ boxes, const int* __restrict__ bidx,
    float* __restrict__ out, int N)
{
  const int tid  = threadIdx.x;
  const int wave = tid >> 6, lane = tid & 63;
  const int n    = blockIdx.y;
  if (n >= N) return;

  // ---- per-box meta (wave-uniform, recomputed by every lane) ----
  const float bx1 = boxes[4*n+0], by1 = boxes[4*n+1];
  const float bx2 = boxes[4*n+2], by2 = boxes[4*n+3];
  const float area = (bx2 - bx1 + 1.0f) * (by2 - by1 + 1.0f);
  const float s    = sqrtf(area);
  int lvl = (int)floorf(4.0f + log2f(s / 224.0f + 1e-6f));
  lvl = lvl < 2 ? 2 : (lvl > 5 ? 5 : lvl);
  const int li = lvl - 2;

  int H, W; const float* feat; float scale;
  switch (li) {
    case 0:  feat = f0; H = 200; W = 304; scale = 0.25f;    break;
    case 1:  feat = f1; H = 100; W = 152; scale = 0.125f;   break;
    case 2:  feat = f2; H = 50;  W = 76;  scale = 0.0625f;  break;
    default: feat = f3; H = 25;  W = 38;  scale = 0.03125f; break;
  }
  const int b = bidx[n];
  const float x1s = bx1 * scale, y1s = by1 * scale;
  const float roiw = fmaxf(bx2 * scale - x1s, 1.0f);
  const float roih = fmaxf(by2 * scale - y1s, 1.0f);
  const float binw = roiw / 7.0f, binh = roih / 7.0f;
  const float Hm1f = (float)(H - 1), Wm1f = (float)(W - 1);
  const int   Hm1  = H - 1,          Wm1  = W - 1;

  // ---- per-lane bin parameters (channel-invariant; lanes 49..63 duplicate bin 0) ----
  const int bin = (lane < 49) ? lane : 0;
  const int ph = bin / 7, pw = bin - (bin / 7) * 7;
  int   y0a[2], y1a[2], x0a[2], x1a[2];
  float HY[2], LY[2], VY[2], HX[2], LX[2], VX[2];
#pragma unroll
  for (int t = 0; t < 2; ++t) {
    {   // y sample index i = 2*ph + t  ->  g = ph + 0.25 + 0.5*t
      const float g  = (float)ph + 0.25f + 0.5f * (float)t;
      const float Yf = y1s + binh * g;
      VY[t] = (Yf >= -1.0f && Yf <= (float)H) ? 1.0f : 0.0f;
      const float y = fminf(fmaxf(Yf, 0.0f), Hm1f);
      const int  y0 = (int)y;
      LY[t] = y - (float)y0;  HY[t] = 1.0f - LY[t];
      y0a[t] = y0;  y1a[t] = min(y0 + 1, Hm1);
    }
    {   // x sample index j = 2*pw + t
      const float g  = (float)pw + 0.25f + 0.5f * (float)t;
      const float Xf = x1s + binw * g;
      VX[t] = (Xf >= -1.0f && Xf <= (float)W) ? 1.0f : 0.0f;
      const float x = fminf(fmaxf(Xf, 0.0f), Wm1f);
      const int  x0 = (int)x;
      LX[t] = x - (float)x0;  HX[t] = 1.0f - LX[t];
      x0a[t] = x0;  x1a[t] = min(x0 + 1, Wm1);
    }
  }

  // ---- 16 taps: element offsets within a plane (channel-invariant) + weights ----
  int   off[16];
  float wt [16];
#pragma unroll
  for (int sy = 0; sy < 2; ++sy) {
#pragma unroll
    for (int sx = 0; sx < 2; ++sx) {
      const float vv = VY[sy] * VX[sx];
      const int q = (sy * 2 + sx) * 4;
      off[q+0] = y0a[sy] * W + x0a[sx];  wt[q+0] = vv * HY[sy] * HX[sx];
      off[q+1] = y0a[sy] * W + x1a[sx];  wt[q+1] = vv * HY[sy] * LX[sx];
      off[q+2] = y1a[sy] * W + x0a[sx];  wt[q+2] = vv * LY[sy] * HX[sx];
      off[q+3] = y1a[sy] * W + x1a[sx];  wt[q+3] = vv * LY[sy] * LX[sx];
    }
  }

  // ---- per-channel loop: 16 channels per wave, processed in pairs ----
  const size_t planeHW = (size_t)H * W;
  const int    cbase   = (blockIdx.x << 5) + (wave << 4);   // 16 channels per wave
  const float* pc0     = feat + ((size_t)(b * 256 + cbase)) * planeHW;
  float*       outp    = out + ((size_t)n * 256 + cbase) * 49 + lane;

#pragma unroll 2
  for (int cp = 0; cp < 8; ++cp) {
    const int ccA = cp * 2, ccB = ccA + 1;
    const float* pA = pc0 + (size_t)ccA * planeHW;
    const float* pB = pc0 + (size_t)ccB * planeHW;
    // load phase: 32 independent loads in flight
    float vA[16], vB[16];
#pragma unroll
    for (int k = 0; k < 16; ++k) vA[k] = pA[off[k]];
#pragma unroll
    for (int k = 0; k < 16; ++k) vB[k] = pB[off[k]];
    // accumulate phase
    float aA = 0.0f, aB = 0.0f;
#pragma unroll
    for (int k = 0; k < 16; ++k) aA += wt[k] * vA[k];
#pragma unroll
    for (int k = 0; k < 16; ++k) aB += wt[k] * vB[k];
    if (lane < 49) {
      outp[ccA * 49] = aA * 0.25f;
      outp[ccB * 49] = aB * 0.25f;
    }
  }
}

extern "C" void kernel_launch(void* const* d_in, const int* in_sizes, int n_in,
                              void* d_out, int out_size, void* d_ws, size_t ws_size,
                              hipStream_t stream) {
  const float* f0    = (const float*)d_in[0];
  const float* f1    = (const float*)d_in[1];
  const float* f2    = (const float*)d_in[2];
  const float* f3    = (const float*)d_in[3];
  const float* boxes = (const float*)d_in[4];
  const int*   bidx  = (const int*)d_in[5];
  const int N = in_sizes[5];                 // 1024 boxes
  dim3 grid(8, N);                           // 8 groups x (2 waves x 16 ch) = 256 channels
  pooler_kernel<<<grid, 128, 0, stream>>>(f0, f1, f2, f3, boxes, bidx,
                                          (float*)d_out, N);
}

// Round 7
// 281.528 us; speedup vs baseline: 1.2376x; 1.2376x over previous
//
#include <hip/hip_runtime.h>
#include <math.h>

#define TILE_F 1792    // floats per wave tile; worst-case region ~1770 (elongated level-0 ROI)
#define B896   896     // 2-deep pipeline buffer (cnt4 <= 224 float4)
#define MAXIP  4       // pipelined staging iterations: ceil(224/64)
#define MAXI   7       // serial staging iterations: ceil(448/64)

typedef __attribute__((address_space(3))) void lds_void;
typedef const __attribute__((address_space(1))) void g_void;

__device__ __forceinline__ void dma16(const float* g, float* l) {
  __builtin_amdgcn_global_load_lds((g_void*)g, (lds_void*)l, 16, 0, 0);
}
// Counted vmcnt wait, wave-uniform k. In-order retire => outstanding<=k implies
// everything older than the newest k ops has completed.
#define WC(N) case N: asm volatile("s_waitcnt vmcnt(" #N ")" ::: "memory"); break;
__device__ __forceinline__ void wait_vmcnt(int k) {
  switch (k) {
    WC(0) WC(1) WC(2) WC(3) WC(4) WC(5) WC(6) WC(7)
    default: asm volatile("s_waitcnt vmcnt(8)" ::: "memory"); break;
  }
}

// 49-lane bilinear 2x2x(2x2) gather + average + store; arrays are unroll-indexed (registers).
#define COMPUTE_STORE(TP, CC)                                                  \
  if (lane < 49) {                                                             \
    float acc = 0.0f;                                                          \
    _Pragma("unroll")                                                          \
    for (int sy = 0; sy < 2; ++sy) {                                           \
      _Pragma("unroll")                                                        \
      for (int sx = 0; sx < 2; ++sx) {                                         \
        const float w00 = (TP)[rT[sy] + Cc0[sx]];                              \
        const float w01 = (TP)[rT[sy] + Cc1[sx]];                              \
        const float w10 = (TP)[rB[sy] + Cc0[sx]];                              \
        const float w11 = (TP)[rB[sy] + Cc1[sx]];                              \
        const float bil = HY[sy] * (HX[sx] * w00 + LX[sx] * w01)               \
                        + LY[sy] * (HX[sx] * w10 + LX[sx] * w11);              \
        acc += (VY[sy] * VX[sx]) * bil;                                        \
      }                                                                        \
    }                                                                          \
    outp[(CC) * 49] = acc * 0.25f;                                             \
  }

// ============ L3 warm-up: stream the whole pyramid sequentially ============
// Sequential address-order reads hit HBM at ~6 TB/s and fill the 256MB
// memory-side Infinity Cache; the pooler's scattered reads then hit L3.
// No writes; loads kept live via empty inline-asm (cannot be DCE'd).
__global__ __launch_bounds__(256) void warm_kernel(
    const float4* __restrict__ f0, int n0, const float4* __restrict__ f1, int n1,
    const float4* __restrict__ f2, int n2, const float4* __restrict__ f3, int n3)
{
  const int stride = gridDim.x * blockDim.x;
  const int idx = blockIdx.x * blockDim.x + threadIdx.x;
  float acc = 0.0f;
  for (int i = idx; i < n0; i += stride) { float4 v = f0[i]; acc += v.x + v.y + v.z + v.w; }
  for (int i = idx; i < n1; i += stride) { float4 v = f1[i]; acc += v.x + v.y + v.z + v.w; }
  for (int i = idx; i < n2; i += stride) { float4 v = f2[i]; acc += v.x + v.y + v.z + v.w; }
  for (int i = idx; i < n3; i += stride) { float4 v = f3[i]; acc += v.x + v.y + v.z + v.w; }
  asm volatile("" :: "v"(acc));   // keep loads live, no memory traffic
}

__global__ __launch_bounds__(128) void pooler_kernel(
    const float* __restrict__ f0, const float* __restrict__ f1,
    const float* __restrict__ f2, const float* __restrict__ f3,
    const float* __restrict__ boxes, const int* __restrict__ bidx,
    float* __restrict__ out, int N)
{
  __shared__ __align__(16) float tile[2][TILE_F];  // 14336 B/block -> 11 blocks/CU
  const int tid  = threadIdx.x;
  const int wave = tid >> 6, lane = tid & 63;
  const int n    = blockIdx.y;
  if (n >= N) return;

  // ---- per-box meta (wave-uniform, recomputed by every lane) ----
  const float bx1 = boxes[4*n+0], by1 = boxes[4*n+1];
  const float bx2 = boxes[4*n+2], by2 = boxes[4*n+3];
  const float area = (bx2 - bx1 + 1.0f) * (by2 - by1 + 1.0f);
  const float s    = sqrtf(area);
  int lvl = (int)floorf(4.0f + log2f(s / 224.0f + 1e-6f));
  lvl = lvl < 2 ? 2 : (lvl > 5 ? 5 : lvl);
  const int li = lvl - 2;

  int H, W; const float* feat; float scale;
  switch (li) {
    case 0:  feat = f0; H = 200; W = 304; scale = 0.25f;    break;
    case 1:  feat = f1; H = 100; W = 152; scale = 0.125f;   break;
    case 2:  feat = f2; H = 50;  W = 76;  scale = 0.0625f;  break;
    default: feat = f3; H = 25;  W = 38;  scale = 0.03125f; break;
  }
  const int b = bidx[n];
  const float x1s = bx1 * scale, y1s = by1 * scale;
  const float roiw = fmaxf(bx2 * scale - x1s, 1.0f);
  const float roih = fmaxf(by2 * scale - y1s, 1.0f);
  const float binw = roiw / 7.0f, binh = roih / 7.0f;
  const float Hm1f = (float)(H - 1), Wm1f = (float)(W - 1);
  const int   Hm1  = H - 1,          Wm1  = W - 1;

  // ---- staged region bounds (samples monotone: first g=0.25, last g=6.75) ----
  const float yA = fminf(fmaxf(y1s + binh * 0.25f, 0.0f), Hm1f);
  const float yB = fminf(fmaxf(y1s + binh * 6.75f, 0.0f), Hm1f);
  const float xA = fminf(fmaxf(x1s + binw * 0.25f, 0.0f), Wm1f);
  const float xB = fminf(fmaxf(x1s + binw * 6.75f, 0.0f), Wm1f);
  const int y_lo  = (int)yA;
  const int y_hi  = min((int)yB + 1, Hm1);
  const int regH  = y_hi - y_lo + 1;
  const int x_lo4 = ((int)xA) & ~3;
  const int x_hi  = min((int)xB + 1, Wm1);
  const int row4  = ((x_hi - x_lo4 + 4) >> 2);
  const int regW4 = row4 << 2;

  // ---- per-lane bin parameters (channel-invariant; lanes 49..63 compute junk) ----
  const int bin = (lane < 49) ? lane : 0;
  const int ph = bin / 7, pw = bin - (bin / 7) * 7;
  int   rT[2], rB[2], Cc0[2], Cc1[2];           // region-relative (LDS paths)
  int   y0a[2], y1a[2], x0a[2], x1a[2];         // absolute (direct path)
  float HY[2], LY[2], VY[2], HX[2], LX[2], VX[2];
#pragma unroll
  for (int t = 0; t < 2; ++t) {
    {
      const float g  = (float)ph + 0.25f + 0.5f * (float)t;
      const float Yf = y1s + binh * g;
      VY[t] = (Yf >= -1.0f && Yf <= (float)H) ? 1.0f : 0.0f;
      const float y = fminf(fmaxf(Yf, 0.0f), Hm1f);
      const int  y0 = (int)y;
      LY[t] = y - (float)y0;  HY[t] = 1.0f - LY[t];
      y0a[t] = y0;  y1a[t] = min(y0 + 1, Hm1);
      rT[t] = (y0 - y_lo) * regW4;
      rB[t] = (y1a[t] - y_lo) * regW4;
    }
    {
      const float g  = (float)pw + 0.25f + 0.5f * (float)t;
      const float Xf = x1s + binw * g;
      VX[t] = (Xf >= -1.0f && Xf <= (float)W) ? 1.0f : 0.0f;
      const float x = fminf(fmaxf(Xf, 0.0f), Wm1f);
      const int  x0 = (int)x;
      LX[t] = x - (float)x0;  HX[t] = 1.0f - LX[t];
      x0a[t] = x0;  x1a[t] = min(x0 + 1, Wm1);
      Cc0[t] = x0 - x_lo4;
      Cc1[t] = x1a[t] - x_lo4;
    }
  }

  // ---- pointers ----
  const size_t planeHW = (size_t)H * W;
  const int    cbase   = (blockIdx.x << 5) + (wave << 4);   // 16 channels per wave
  const float* plane0  = feat + ((size_t)(b * 256 + cbase)) * planeHW
                              + (size_t)y_lo * W;
  float*       outp    = out + ((size_t)n * 256 + cbase) * 49 + lane;
  float*       myt     = tile[wave];

  if (li == 3) {
    // ======== level-3 direct path: plane is 3.8 KB (cache-hot). No LDS, no DMA. ========
    int   off[2][2][4];
    float wt [2][2][4];
#pragma unroll
    for (int sy = 0; sy < 2; ++sy) {
#pragma unroll
      for (int sx = 0; sx < 2; ++sx) {
        const float vv = VY[sy] * VX[sx];
        off[sy][sx][0] = y0a[sy] * 38 + x0a[sx];  wt[sy][sx][0] = vv * HY[sy] * HX[sx];
        off[sy][sx][1] = y0a[sy] * 38 + x1a[sx];  wt[sy][sx][1] = vv * HY[sy] * LX[sx];
        off[sy][sx][2] = y1a[sy] * 38 + x0a[sx];  wt[sy][sx][2] = vv * LY[sy] * HX[sx];
        off[sy][sx][3] = y1a[sy] * 38 + x1a[sx];  wt[sy][sx][3] = vv * LY[sy] * LX[sx];
      }
    }
    const float* pc0 = feat + ((size_t)(b * 256 + cbase)) * planeHW;  // no y_lo offset
#pragma unroll 2
    for (int cc = 0; cc < 16; ++cc) {
      const float* pc = pc0 + (size_t)cc * planeHW;
      float acc = 0.0f;
#pragma unroll
      for (int sy = 0; sy < 2; ++sy)
#pragma unroll
        for (int sx = 0; sx < 2; ++sx)
#pragma unroll
          for (int k = 0; k < 4; ++k)
            acc += wt[sy][sx][k] * pc[off[sy][sx][k]];
      if (lane < 49) outp[cc * 49] = acc * 0.25f;
    }
  } else {
    int cnt4 = regH * row4;
    if (cnt4 > TILE_F / 4) cnt4 = TILE_F / 4;   // safety (analysis: <=~443)
    // exact magic-divide by row4 (u*row4 < 65536 for all paths: 447*76 < 65536)
    const int Mrow = (int)(65536.0f / (float)row4) + 1;
    const int K = (cnt4 + 63) >> 6;

    if (cnt4 <= B896 / 4) {
      // ======== pipelined path: 2 x 896, store-aware counted waits ========
      int soff[MAXIP];
#pragma unroll
      for (int i = 0; i < MAXIP; ++i) {
        const int u = lane + (i << 6);
        if (u < cnt4) {
          const int r = (u * Mrow) >> 16;
          const int c = u - r * row4;
          soff[i] = r * W + x_lo4 + (c << 2);
        } else soff[i] = -1;
      }
      // prologue: channel 0 -> buffer 0
#pragma unroll
      for (int i = 0; i < MAXIP; ++i)
        if (soff[i] >= 0) dma16(plane0 + soff[i], myt + (i << 8));

      for (int cc = 0; cc < 16; ++cc) {
        asm volatile("s_waitcnt lgkmcnt(0)" ::: "memory");
        if (cc + 1 < 16) {
          const float* pl = plane0 + (size_t)(cc + 1) * planeHW;
          float* bf = myt + (((cc + 1) & 1) ? B896 : 0);
#pragma unroll
          for (int i = 0; i < MAXIP; ++i)
            if (soff[i] >= 0) dma16(pl + soff[i], bf + (i << 8));
        }
        wait_vmcnt(cc == 0 ? K : (cc == 15 ? 1 : K + 1));
        const float* bufC = myt + ((cc & 1) ? B896 : 0);
        COMPUTE_STORE(bufC, cc)
      }
    } else {
      // ======== serial fallback (rare elongated boxes): full 1792-float tile ========
      int soff[MAXI];
#pragma unroll
      for (int i = 0; i < MAXI; ++i) {
        const int u = lane + (i << 6);
        if (u < cnt4) {
          const int r = (u * Mrow) >> 16;
          const int c = u - r * row4;
          soff[i] = r * W + x_lo4 + (c << 2);
        } else soff[i] = -1;
      }
      for (int cc = 0; cc < 16; ++cc) {
        const float* plane = plane0 + (size_t)cc * planeHW;
        asm volatile("s_waitcnt lgkmcnt(0)" ::: "memory");
#pragma unroll
        for (int i = 0; i < MAXI; ++i)
          if (soff[i] >= 0) dma16(plane + soff[i], myt + (i << 8));
        asm volatile("s_waitcnt vmcnt(0)" ::: "memory");
        COMPUTE_STORE(myt, cc)
      }
    }
  }
}

extern "C" void kernel_launch(void* const* d_in, const int* in_sizes, int n_in,
                              void* d_out, int out_size, void* d_ws, size_t ws_size,
                              hipStream_t stream) {
  const float* f0    = (const float*)d_in[0];
  const float* f1    = (const float*)d_in[1];
  const float* f2    = (const float*)d_in[2];
  const float* f3    = (const float*)d_in[3];
  const float* boxes = (const float*)d_in[4];
  const int*   bidx  = (const int*)d_in[5];
  const int N = in_sizes[5];                 // 1024 boxes

  // Pass 1: sequential L3 warm (HBM streams at ~6 TB/s in address order).
  // float4 counts: f0 2*256*200*304/4, f1 /4 sizes etc.
  warm_kernel<<<dim3(2048), 256, 0, stream>>>(
      (const float4*)f0, 2*256*200*304/4, (const float4*)f1, 2*256*100*152/4,
      (const float4*)f2, 2*256*50*76/4,   (const float4*)f3, 2*256*25*38/4);

  // Pass 2: unchanged R4 pooler (stream-ordered after warm; reads hit L3).
  dim3 grid(8, N);                           // 8 groups x (2 waves x 16 ch) = 256 channels
  pooler_kernel<<<grid, 128, 0, stream>>>(f0, f1, f2, f3, boxes, bidx,
                                          (float*)d_out, N);
}